// Round 1
// 78.988 us; speedup vs baseline: 1.0001x; 1.0001x over previous
//
#include <hip/hip_runtime.h>
#include <math.h>

// Kalman filter: gains are data-independent => output is linear in obs:
//   X_T = sum_l (A^l K) z_{T-1-l},  A = (I-KH)F at the Riccati fixed point,
// with A^l decaying geometrically => 64 taps suffice at fp32.
//
// Grid 256 blocks x 256 threads = exactly 1 block/CU: each CU has exactly ONE
// weight-computing wave (wave 0), so the ~7k-cycle serial Riccati burn never
// serializes multiple blocks' compute-waves onto the same SIMD (the previous
// 1024-block version put 4 compute-waves on SIMD0 of each CU).
// Each wave handles 4 batches (16 per block); all z loads issued at entry.

#define BURN 24    // Riccati contracts at rho^2/iter; rho <= ~0.6 here
#define T_LEN 1024

__global__ __launch_bounds__(256) void kf_fused_kernel(
    const float* __restrict__ hist, const float* __restrict__ Qlog,
    const float* __restrict__ Rlog, float* __restrict__ out) {
  const int l = threadIdx.x & 63;          // lane = tap index
  const int w = threadIdx.x >> 6;          // wave within block
  const int b0 = blockIdx.x * 16 + w * 4;  // first of this wave's 4 batches

  // Issue all data loads immediately; first use is after the barrier.
  float2 z[4];
#pragma unroll
  for (int j = 0; j < 4; ++j)
    z[j] = *(const float2*)(hist + (size_t)(b0 + j) * (2 * T_LEN) +
                            (size_t)(2046 - 2 * l));

  __shared__ float4 Wsh[128];  // Wsh[tap*2 + c] = (state0..3) weight, obs comp c

  if (w == 0) {
    float q[16], r[4];
#pragma unroll
    for (int i = 0; i < 16; ++i) q[i] = __expf(Qlog[i]);
    q[0] += 1e-6f; q[5] += 1e-6f; q[10] += 1e-6f; q[15] += 1e-6f;
#pragma unroll
    for (int i = 0; i < 4; ++i) r[i] = __expf(Rlog[i]);
    r[0] += 1e-6f; r[3] += 1e-6f;

    // Riccati burn-in (all 64 lanes redundant, ILP-rich)
    float P[16];
#pragma unroll
    for (int i = 0; i < 16; ++i) P[i] = 0.f;
    P[0] = P[5] = P[10] = P[15] = 1000.f;
    float K[8];  // K[i*2+c]

    for (int it = 0; it < BURN; ++it) {
      float a[16];  // F P F^T + Q
#pragma unroll
      for (int i = 0; i < 4; ++i)
#pragma unroll
        for (int j = 0; j < 4; ++j) {
          float v = P[i * 4 + j];
          if (i < 2) v += P[(i + 2) * 4 + j];
          if (j < 2) v += P[i * 4 + j + 2];
          if (i < 2 && j < 2) v += P[(i + 2) * 4 + (j + 2)];
          a[i * 4 + j] = v + q[i * 4 + j];
        }
      // S = a[0:2,0:2] + R ; general 2x2 inverse (Q,R asymmetric => S asymmetric)
      float s00 = a[0] + r[0], s01 = a[1] + r[1];
      float s10 = a[4] + r[2], s11 = a[5] + r[3];
      float inv_det = __builtin_amdgcn_rcpf(s00 * s11 - s01 * s10);
      float i00 = s11 * inv_det, i01 = -s01 * inv_det;
      float i10 = -s10 * inv_det, i11 = s00 * inv_det;
#pragma unroll
      for (int i = 0; i < 4; ++i) {
        K[i * 2 + 0] = a[i * 4 + 0] * i00 + a[i * 4 + 1] * i10;
        K[i * 2 + 1] = a[i * 4 + 0] * i01 + a[i * 4 + 1] * i11;
      }
      // P = (I - K H) a = a - K * a[0:2,:]
#pragma unroll
      for (int i = 0; i < 4; ++i)
#pragma unroll
        for (int j = 0; j < 4; ++j)
          P[i * 4 + j] = a[i * 4 + j] - K[i * 2 + 0] * a[j] - K[i * 2 + 1] * a[4 + j];
    }

    // A = (I - K H) F
    float M[16];
#pragma unroll
    for (int i = 0; i < 4; ++i)
#pragma unroll
      for (int j = 0; j < 4; ++j) {
        float m = (i == j) ? 1.f : 0.f;
        if (j < 2) m -= K[i * 2 + j];
        M[i * 4 + j] = m;
      }
    float A[16];
#pragma unroll
    for (int i = 0; i < 4; ++i) {
      A[i * 4 + 0] = M[i * 4 + 0];
      A[i * 4 + 1] = M[i * 4 + 1];
      A[i * 4 + 2] = M[i * 4 + 0] + M[i * 4 + 2];
      A[i * 4 + 3] = M[i * 4 + 1] + M[i * 4 + 3];
    }

    // G_l = A^l K per lane via bit-doubling applied DIRECTLY to the 4x2 tap
    // matrix (powers of A commute, so applying selected A^(2^d) in any order
    // equals A^l). 4x2 select-matmul (32 FMA) replaces the old 4x4 (64 FMA).
    float G[8], Bm[16];
#pragma unroll
    for (int i = 0; i < 8; ++i) G[i] = K[i];
#pragma unroll
    for (int i = 0; i < 16; ++i) Bm[i] = A[i];
#pragma unroll
    for (int d = 0; d < 6; ++d) {
      float C[8];
#pragma unroll
      for (int i = 0; i < 4; ++i)
#pragma unroll
        for (int c = 0; c < 2; ++c) {
          float s = 0.f;
#pragma unroll
          for (int kk = 0; kk < 4; ++kk) s += Bm[i * 4 + kk] * G[kk * 2 + c];
          C[i * 2 + c] = s;
        }
      const bool bit = (l >> d) & 1;
#pragma unroll
      for (int i = 0; i < 8; ++i) G[i] = bit ? C[i] : G[i];
      if (d < 5) {
        float B2[16];
#pragma unroll
        for (int i = 0; i < 4; ++i)
#pragma unroll
          for (int j = 0; j < 4; ++j) {
            float s = 0.f;
#pragma unroll
            for (int kk = 0; kk < 4; ++kk) s += Bm[i * 4 + kk] * Bm[kk * 4 + j];
            B2[i * 4 + j] = s;
          }
#pragma unroll
        for (int i = 0; i < 16; ++i) Bm[i] = B2[i];
      }
    }

    Wsh[l * 2 + 0] = make_float4(G[0], G[2], G[4], G[6]);
    Wsh[l * 2 + 1] = make_float4(G[1], G[3], G[5], G[7]);
  }

  __syncthreads();

  const float4 w0 = Wsh[2 * l + 0];  // obs comp 0 weights, states 0..3
  const float4 w1 = Wsh[2 * l + 1];  // obs comp 1
#pragma unroll
  for (int j = 0; j < 4; ++j) {
    float x0 = w0.x * z[j].x + w1.x * z[j].y;
    float x1 = w0.y * z[j].x + w1.y * z[j].y;
    float x2 = w0.z * z[j].x + w1.z * z[j].y;
    float x3 = w0.w * z[j].x + w1.w * z[j].y;
#pragma unroll
    for (int off = 32; off > 0; off >>= 1) {
      x0 += __shfl_xor(x0, off);
      x1 += __shfl_xor(x1, off);
      x2 += __shfl_xor(x2, off);
      x3 += __shfl_xor(x3, off);
    }
    if (l == 0) {
      float* o = out + (size_t)(b0 + j) * 6;
      *(float2*)(o + 0) = make_float2(x0 + x2, x1 + x3);
      *(float2*)(o + 2) = make_float2(x0 + 2.f * x2, x1 + 2.f * x3);
      *(float2*)(o + 4) = make_float2(x0 + 3.f * x2, x1 + 3.f * x3);
    }
  }
}

extern "C" void kernel_launch(void* const* d_in, const int* in_sizes, int n_in,
                              void* d_out, int out_size, void* d_ws, size_t ws_size,
                              hipStream_t stream) {
  const float* hist = (const float*)d_in[0];
  const float* Qlog = (const float*)d_in[1];
  const float* Rlog = (const float*)d_in[2];
  kf_fused_kernel<<<256, 256, 0, stream>>>(hist, Qlog, Rlog, (float*)d_out);
}